// Round 1
// baseline (226.488 us; speedup 1.0000x reference)
//
#include <hip/hip_runtime.h>

namespace {
constexpr int TOK = 8192;
constexpr int DIM = 4096;
constexpr int NE  = 64;
constexpr int TB  = 128;          // tokens per gemm tile
constexpr int KS  = 8;            // split-K factor
constexpr int KR  = DIM / KS;     // 512 k per block
constexpr int BK  = 32;           // k per LDS stage
constexpr int NT  = TOK / TB;     // 64 token tiles
constexpr int NITER = KR / BK;    // 16
constexpr int ATS = TB + 4;       // 132: pad keeps ds_read_b128 16B-aligned, 2-way banks
constexpr int BTS = NE + 4;       // 68
constexpr int GB  = 64;           // tokens per gating chunk
constexpr int NCH = TOK / GB;     // 128 chunks
}

// ---------------------------------------------------------------------------
// Split-K fp32 GEMM: logits_partial[ks][t][e] = A[t, ks*KR:(ks+1)*KR] . W[e, ...]
// 512 blocks x 128 threads; per-thread 8x8 register tile (LDS/VALU balanced).
// ---------------------------------------------------------------------------
__global__ __launch_bounds__(128) void gemm_split(
    const float* __restrict__ A, const float* __restrict__ W,
    float* __restrict__ partial) {
  __shared__ float As[BK * ATS];   // k-major: As[k][token]
  __shared__ float Bs[BK * BTS];   // k-major: Bs[k][expert]
  const int bid  = blockIdx.x;
  const int tile = bid & (NT - 1);
  const int ks   = bid / NT;
  const int t0   = tile * TB;
  const int k0   = ks * KR;
  const int tid  = threadIdx.x;

  float4 ra[8];
  float4 rb[4];

  // prefetch stage 0 into registers
  {
    const int kb = k0;
#pragma unroll
    for (int j = 0; j < 8; ++j) {
      const int idx = tid + 128 * j;
      const int rr = idx >> 3, cc = (idx & 7) * 4;
      ra[j] = *(const float4*)(A + (size_t)(t0 + rr) * DIM + kb + cc);
    }
#pragma unroll
    for (int j = 0; j < 4; ++j) {
      const int idx = tid + 128 * j;
      const int ee = idx >> 3, cc = (idx & 7) * 4;
      rb[j] = *(const float4*)(W + (size_t)ee * DIM + kb + cc);
    }
  }

  float acc[8][8];
#pragma unroll
  for (int i = 0; i < 8; ++i)
#pragma unroll
    for (int j = 0; j < 8; ++j) acc[i][j] = 0.0f;

  const int ta = (tid >> 3) * 8;   // token offset of this thread's tile
  const int ea = (tid & 7) * 8;    // expert offset

  for (int it = 0; it < NITER; ++it) {
    __syncthreads();               // previous compute done; LDS reusable
    // transpose-store staged registers into k-major LDS
#pragma unroll
    for (int j = 0; j < 8; ++j) {
      const int idx = tid + 128 * j;
      const int rr = idx >> 3, cc = (idx & 7) * 4;
      As[(cc + 0) * ATS + rr] = ra[j].x;
      As[(cc + 1) * ATS + rr] = ra[j].y;
      As[(cc + 2) * ATS + rr] = ra[j].z;
      As[(cc + 3) * ATS + rr] = ra[j].w;
    }
#pragma unroll
    for (int j = 0; j < 4; ++j) {
      const int idx = tid + 128 * j;
      const int ee = idx >> 3, cc = (idx & 7) * 4;
      Bs[(cc + 0) * BTS + ee] = rb[j].x;
      Bs[(cc + 1) * BTS + ee] = rb[j].y;
      Bs[(cc + 2) * BTS + ee] = rb[j].z;
      Bs[(cc + 3) * BTS + ee] = rb[j].w;
    }
    __syncthreads();
    // prefetch next stage (overlaps with compute below)
    if (it + 1 < NITER) {
      const int kb = k0 + (it + 1) * BK;
#pragma unroll
      for (int j = 0; j < 8; ++j) {
        const int idx = tid + 128 * j;
        const int rr = idx >> 3, cc = (idx & 7) * 4;
        ra[j] = *(const float4*)(A + (size_t)(t0 + rr) * DIM + kb + cc);
      }
#pragma unroll
      for (int j = 0; j < 4; ++j) {
        const int idx = tid + 128 * j;
        const int ee = idx >> 3, cc = (idx & 7) * 4;
        rb[j] = *(const float4*)(W + (size_t)ee * DIM + kb + cc);
      }
    }
    // compute: 32 k-steps x 64 FMA/thread
#pragma unroll 8
    for (int k = 0; k < BK; ++k) {
      const float4 a0 = *(const float4*)(As + k * ATS + ta);
      const float4 a1 = *(const float4*)(As + k * ATS + ta + 4);
      const float4 b0 = *(const float4*)(Bs + k * BTS + ea);
      const float4 b1 = *(const float4*)(Bs + k * BTS + ea + 4);
      const float av[8] = {a0.x, a0.y, a0.z, a0.w, a1.x, a1.y, a1.z, a1.w};
      const float bv[8] = {b0.x, b0.y, b0.z, b0.w, b1.x, b1.y, b1.z, b1.w};
#pragma unroll
      for (int i = 0; i < 8; ++i)
#pragma unroll
        for (int j = 0; j < 8; ++j) acc[i][j] += av[i] * bv[j];
    }
  }

  float* P = partial + (size_t)ks * TOK * NE;
#pragma unroll
  for (int i = 0; i < 8; ++i) {
    const int t = t0 + ta + i;
    *(float4*)(P + (size_t)t * NE + ea) =
        make_float4(acc[i][0], acc[i][1], acc[i][2], acc[i][3]);
    *(float4*)(P + (size_t)t * NE + ea + 4) =
        make_float4(acc[i][4], acc[i][5], acc[i][6], acc[i][7]);
  }
}

// ---------------------------------------------------------------------------
// Gating: sum split-K partials -> logits; argmax / softmax / per-chunk rank +
// histogram; me[] accumulated via one atomicAdd per expert per block.
// ---------------------------------------------------------------------------
__global__ __launch_bounds__(256) void gating(
    const float* __restrict__ partial, float* __restrict__ out,
    int* __restrict__ idx_int, int* __restrict__ rankp,
    int* __restrict__ hist, float* __restrict__ me) {
  __shared__ float L[GB * 65];     // 64 tokens x 64 logits, stride 65 (bank-safe)
  __shared__ float mx[GB];
  __shared__ float dninv[GB];
  __shared__ int   eid[GB];
  const int b = blockIdx.x, tid = threadIdx.x;
  const size_t base = (size_t)b * GB * NE;

#pragma unroll
  for (int j = 0; j < (GB * NE) / 256; ++j) {   // 16 elements / thread
    const int idx = tid + 256 * j;
    float s = 0.0f;
#pragma unroll
    for (int k = 0; k < KS; ++k)
      s += partial[(size_t)k * TOK * NE + base + idx];
    L[(idx >> 6) * 65 + (idx & 63)] = s;
  }
  __syncthreads();

  if (tid < GB) {  // one thread per token: argmax (first-occurrence) + softmax
    const int t = tid;
    float m = -3.0e38f; int bi = 0;
    for (int e = 0; e < NE; ++e) {
      const float v = L[t * 65 + e];
      if (v > m) { m = v; bi = e; }
    }
    float s = 0.0f;
    for (int e = 0; e < NE; ++e) s += __expf(L[t * 65 + e] - m);
    const float inv = 1.0f / s;
    mx[t] = m; dninv[t] = inv; eid[t] = bi;
    const int gt = b * GB + t;
    out[1 + gt]           = (float)bi;   // indices1_s
    out[1 + 2 * TOK + gt] = inv;         // gates1_s = softmax at argmax
    idx_int[gt] = bi;
  }
  __syncthreads();

  if (tid < GB) {  // within-chunk rank + chunk histogram (GB == NE == 64)
    const int t = tid, e = eid[t];
    int r = 0;
    for (int j = 0; j < t; ++j) r += (eid[j] == e) ? 1 : 0;
    rankp[b * GB + t] = r;
    int c = 0;
    for (int t2 = 0; t2 < GB; ++t2) c += (eid[t2] == tid) ? 1 : 0;
    hist[b * NE + tid] = c;
  } else if (tid < 2 * GB) {  // wave 1: me[e] partial sums
    const int e = tid - GB;
    float s = 0.0f;
    for (int t2 = 0; t2 < GB; ++t2)
      s += __expf(L[t2 * 65 + e] - mx[t2]) * dninv[t2];
    atomicAdd(&me[e], s);
  }
}

// ---------------------------------------------------------------------------
// Finalize: per-expert exclusive prefix over chunk histograms -> locations;
// ce totals + me -> l_aux.
// ---------------------------------------------------------------------------
__global__ __launch_bounds__(256) void finalize(
    const int* __restrict__ idx_int, const int* __restrict__ rankp,
    const int* __restrict__ hist, const float* __restrict__ me,
    float* __restrict__ out) {
  __shared__ int   H[NCH * NE];   // 8192 ints = 32 KB
  __shared__ float CE[NE];
  const int tid = threadIdx.x;
  for (int j = tid; j < NCH * NE; j += 256) H[j] = hist[j];
  __syncthreads();
  if (tid < NE) {  // exclusive scan over chunks, per expert
    int run = 0;
    for (int b = 0; b < NCH; ++b) {
      const int v = H[b * NE + tid];
      H[b * NE + tid] = run;
      run += v;
    }
    CE[tid] = (float)run;  // ce[e]
  }
  __syncthreads();
  if (tid < 64) {  // l_aux = sum(me*ce) * E / T^2   (wave 0 reduce)
    float p = me[tid] * CE[tid];
#pragma unroll
    for (int off = 32; off > 0; off >>= 1) p += __shfl_down(p, off);
    if (tid == 0) out[0] = p * ((float)NE / ((float)TOK * (float)TOK));
  }
  for (int i = tid; i < TOK; i += 256) {  // locations1_s
    const int e = idx_int[i];
    out[1 + TOK + i] = (float)(H[(i >> 6) * NE + e] + rankp[i]);
  }
}

extern "C" void kernel_launch(void* const* d_in, const int* in_sizes, int n_in,
                              void* d_out, int out_size, void* d_ws, size_t ws_size,
                              hipStream_t stream) {
  const float* A = (const float*)d_in[0];   // [8192, 4096] fp32
  const float* W = (const float*)d_in[1];   // [64, 4096] fp32
  float* out = (float*)d_out;               // 1 + 8192*3 floats
  char* ws = (char*)d_ws;

  float* partial = (float*)ws;                                  // 16 MB
  const size_t poff = (size_t)KS * TOK * NE * sizeof(float);
  float* me     = (float*)(ws + poff);                          // 64 floats
  int*  idx_int = (int*)(ws + poff + 1024);                     // 8192 ints
  int*  rankp   = idx_int + TOK;                                // 8192 ints
  int*  hist    = rankp + TOK;                                  // NCH*NE ints

  hipMemsetAsync(me, 0, NE * sizeof(float), stream);
  hipLaunchKernelGGL(gemm_split, dim3(NT * KS), dim3(128), 0, stream, A, W, partial);
  hipLaunchKernelGGL(gating, dim3(NCH), dim3(256), 0, stream, partial, out,
                     idx_int, rankp, hist, me);
  hipLaunchKernelGGL(finalize, dim3(1), dim3(256), 0, stream, idx_int, rankp,
                     hist, me, out);
}

// Round 2
// 211.967 us; speedup vs baseline: 1.0685x; 1.0685x over previous
//
#include <hip/hip_runtime.h>

namespace {
constexpr int TOK = 8192;
constexpr int DIM = 4096;
constexpr int NE  = 64;
constexpr int TB  = 128;          // tokens per gemm tile
constexpr int KS  = 8;            // split-K factor
constexpr int KR  = DIM / KS;     // 512 k per block
constexpr int BK  = 32;           // fp32 k per LDS stage (= one K32 fp16 MFMA)
constexpr int NT  = TOK / TB;     // 64 token tiles
constexpr int NITER = KR / BK;    // 16
constexpr int LSTR = 40;          // LDS row stride in halves: 16B-aligned, 2-way banks
constexpr int GB  = 64;           // tokens per gating chunk
constexpr int NCH = TOK / GB;     // 128 chunks
}

typedef _Float16 f16x8 __attribute__((ext_vector_type(8)));
typedef _Float16 f16x4 __attribute__((ext_vector_type(4)));
typedef float    f32x4 __attribute__((ext_vector_type(4)));

// ---------------------------------------------------------------------------
// Split-K GEMM via fp16x2-split MFMA: logits ~= Ahi*Bhi + Ahi*Blo + Alo*Bhi.
// 512 blocks x 256 threads (4 waves); wave w: tokens [w*32, w*32+32) x 64 experts
// = 2 Mtiles x 4 Etiles of 16x16. Row-major K-contiguous LDS -> no transpose.
// ---------------------------------------------------------------------------
__global__ __launch_bounds__(256) void gemm_split(
    const float* __restrict__ A, const float* __restrict__ W,
    float* __restrict__ partial) {
  __shared__ _Float16 sm[(2 * TB + 2 * NE) * LSTR];  // Ahi|Alo|Whi|Wlo, 30 KB
  _Float16* sAhi = sm;
  _Float16* sAlo = sm + TB * LSTR;
  _Float16* sWhi = sm + 2 * TB * LSTR;
  _Float16* sWlo = sm + 2 * TB * LSTR + NE * LSTR;

  const int bid  = blockIdx.x;
  const int tile = bid & (NT - 1);
  const int ks   = bid / NT;
  const int t0   = tile * TB;
  const int k0   = ks * KR;
  const int tid  = threadIdx.x;
  const int w    = tid >> 6;        // wave id 0..3
  const int lane = tid & 63;
  const int col  = lane & 15;       // MFMA n/m low bits
  const int quad = lane >> 4;       // k chunk + C row group

  float4 ra[4], rw[2];
  // prefetch stage 0
  {
#pragma unroll
    for (int j = 0; j < 4; ++j) {
      const int f4 = tid + 256 * j;              // 1024 float4 = 128 tok x 32 k
      const int tk = f4 >> 3, kc = (f4 & 7) * 4;
      ra[j] = *(const float4*)(A + (size_t)(t0 + tk) * DIM + k0 + kc);
    }
#pragma unroll
    for (int j = 0; j < 2; ++j) {
      const int f4 = tid + 256 * j;              // 512 float4 = 64 e x 32 k
      const int ee = f4 >> 3, kc = (f4 & 7) * 4;
      rw[j] = *(const float4*)(W + (size_t)ee * DIM + k0 + kc);
    }
  }

  f32x4 acc[2][4];
#pragma unroll
  for (int i = 0; i < 2; ++i)
#pragma unroll
    for (int j = 0; j < 4; ++j) acc[i][j] = (f32x4)0.0f;

  for (int it = 0; it < NITER; ++it) {
    __syncthreads();               // previous stage's frag reads done
    // convert fp32 -> (hi, lo) fp16 pairs, store row-major K-contiguous
#pragma unroll
    for (int j = 0; j < 4; ++j) {
      const int f4 = tid + 256 * j;
      const int tk = f4 >> 3, kc = (f4 & 7) * 4;
      const float4 r = ra[j];
      const _Float16 hx = (_Float16)r.x, hy = (_Float16)r.y,
                     hz = (_Float16)r.z, hw = (_Float16)r.w;
      *(f16x4*)(sAhi + tk * LSTR + kc) = (f16x4){hx, hy, hz, hw};
      *(f16x4*)(sAlo + tk * LSTR + kc) =
          (f16x4){(_Float16)(r.x - (float)hx), (_Float16)(r.y - (float)hy),
                  (_Float16)(r.z - (float)hz), (_Float16)(r.w - (float)hw)};
    }
#pragma unroll
    for (int j = 0; j < 2; ++j) {
      const int f4 = tid + 256 * j;
      const int ee = f4 >> 3, kc = (f4 & 7) * 4;
      const float4 r = rw[j];
      const _Float16 hx = (_Float16)r.x, hy = (_Float16)r.y,
                     hz = (_Float16)r.z, hw = (_Float16)r.w;
      *(f16x4*)(sWhi + ee * LSTR + kc) = (f16x4){hx, hy, hz, hw};
      *(f16x4*)(sWlo + ee * LSTR + kc) =
          (f16x4){(_Float16)(r.x - (float)hx), (_Float16)(r.y - (float)hy),
                  (_Float16)(r.z - (float)hz), (_Float16)(r.w - (float)hw)};
    }
    __syncthreads();
    // prefetch next stage (overlaps with MFMA below)
    if (it + 1 < NITER) {
      const int kb = k0 + (it + 1) * BK;
#pragma unroll
      for (int j = 0; j < 4; ++j) {
        const int f4 = tid + 256 * j;
        const int tk = f4 >> 3, kc = (f4 & 7) * 4;
        ra[j] = *(const float4*)(A + (size_t)(t0 + tk) * DIM + kb + kc);
      }
#pragma unroll
      for (int j = 0; j < 2; ++j) {
        const int f4 = tid + 256 * j;
        const int ee = f4 >> 3, kc = (f4 & 7) * 4;
        rw[j] = *(const float4*)(W + (size_t)ee * DIM + kb + kc);
      }
    }
    // fragments: A[m = w*32 + mt*16 + col][k = quad*8 + j]
    f16x8 ah[2], al[2], bh[4], bl[4];
#pragma unroll
    for (int mt = 0; mt < 2; ++mt) {
      const int r = w * 32 + mt * 16 + col;
      ah[mt] = *(const f16x8*)(sAhi + r * LSTR + quad * 8);
      al[mt] = *(const f16x8*)(sAlo + r * LSTR + quad * 8);
    }
#pragma unroll
    for (int et = 0; et < 4; ++et) {
      const int e = et * 16 + col;
      bh[et] = *(const f16x8*)(sWhi + e * LSTR + quad * 8);
      bl[et] = *(const f16x8*)(sWlo + e * LSTR + quad * 8);
    }
#pragma unroll
    for (int mt = 0; mt < 2; ++mt)
#pragma unroll
      for (int et = 0; et < 4; ++et) {
        acc[mt][et] = __builtin_amdgcn_mfma_f32_16x16x32_f16(
            ah[mt], bh[et], acc[mt][et], 0, 0, 0);
        acc[mt][et] = __builtin_amdgcn_mfma_f32_16x16x32_f16(
            ah[mt], bl[et], acc[mt][et], 0, 0, 0);
        acc[mt][et] = __builtin_amdgcn_mfma_f32_16x16x32_f16(
            al[mt], bh[et], acc[mt][et], 0, 0, 0);
      }
  }

  // epilogue: C/D layout col=lane&15 (expert), row=quad*4+reg (token)
  float* P = partial + (size_t)ks * TOK * NE;
#pragma unroll
  for (int mt = 0; mt < 2; ++mt)
#pragma unroll
    for (int et = 0; et < 4; ++et) {
      const int e = et * 16 + col;
#pragma unroll
      for (int r = 0; r < 4; ++r) {
        const int t = t0 + w * 32 + mt * 16 + quad * 4 + r;
        P[(size_t)t * NE + e] = acc[mt][et][r];
      }
    }
}

// ---------------------------------------------------------------------------
// Gating: sum split-K partials -> logits; argmax / softmax / per-chunk rank +
// histogram; me partials per block (no atomics).
// ---------------------------------------------------------------------------
__global__ __launch_bounds__(256) void gating(
    const float* __restrict__ partial, float* __restrict__ out,
    int* __restrict__ idx_int, int* __restrict__ rankp,
    int* __restrict__ hist, float* __restrict__ me_part) {
  __shared__ float L[GB * 65];     // 64 tokens x 64 logits, stride 65
  __shared__ float mx[GB];
  __shared__ float dninv[GB];
  __shared__ int   eid[GB];
  const int b = blockIdx.x, tid = threadIdx.x;
  const size_t base = (size_t)b * GB * NE;

#pragma unroll
  for (int j = 0; j < (GB * NE) / 256; ++j) {   // 16 elements / thread
    const int idx = tid + 256 * j;
    float s = 0.0f;
#pragma unroll
    for (int k = 0; k < KS; ++k)
      s += partial[(size_t)k * TOK * NE + base + idx];
    L[(idx >> 6) * 65 + (idx & 63)] = s;
  }
  __syncthreads();

  if (tid < GB) {  // one thread per token: argmax (first-occurrence) + softmax
    const int t = tid;
    float m = -3.0e38f; int bi = 0;
    for (int e = 0; e < NE; ++e) {
      const float v = L[t * 65 + e];
      if (v > m) { m = v; bi = e; }
    }
    float s = 0.0f;
    for (int e = 0; e < NE; ++e) s += __expf(L[t * 65 + e] - m);
    const float inv = 1.0f / s;
    mx[t] = m; dninv[t] = inv; eid[t] = bi;
    const int gt = b * GB + t;
    out[1 + gt]           = (float)bi;   // indices1_s
    out[1 + 2 * TOK + gt] = inv;         // gates1_s
    idx_int[gt] = bi;
  }
  __syncthreads();

  if (tid < GB) {  // within-chunk rank + chunk histogram
    const int t = tid, e = eid[t];
    int r = 0;
    for (int j = 0; j < t; ++j) r += (eid[j] == e) ? 1 : 0;
    rankp[b * GB + t] = r;
    int c = 0;
    for (int t2 = 0; t2 < GB; ++t2) c += (eid[t2] == tid) ? 1 : 0;
    hist[b * NE + tid] = c;
  } else if (tid < 2 * GB) {  // wave 1: me[e] partial sum for this chunk
    const int e = tid - GB;
    float s = 0.0f;
    for (int t2 = 0; t2 < GB; ++t2)
      s += __expf(L[t2 * 65 + e] - mx[t2]) * dninv[t2];
    me_part[b * NE + e] = s;
  }
}

// ---------------------------------------------------------------------------
// Finalize: segmented per-expert exclusive scan over chunk hists -> locations;
// ce + me reduce -> l_aux.
// ---------------------------------------------------------------------------
__global__ __launch_bounds__(256) void finalize(
    const int* __restrict__ idx_int, const int* __restrict__ rankp,
    const int* __restrict__ hist, const float* __restrict__ me_part,
    float* __restrict__ out) {
  __shared__ int   H[NCH * NE];    // 32 KB
  __shared__ int   SEG[4 * NE];
  __shared__ float MEp[4 * NE];
  __shared__ float CE[NE];
  const int tid = threadIdx.x;
  const int e = tid & 63, seg = tid >> 6;   // 4 segments x 32 chunks

  for (int j = tid; j < NCH * NE; j += 256) H[j] = hist[j];
  {
    float s = 0.0f;
    for (int c = seg * 32; c < seg * 32 + 32; ++c) s += me_part[c * NE + e];
    MEp[seg * NE + e] = s;
  }
  __syncthreads();
  {
    int hs = 0;
    for (int c = seg * 32; c < seg * 32 + 32; ++c) hs += H[c * NE + e];
    SEG[seg * NE + e] = hs;
  }
  __syncthreads();
  if (tid < NE) {  // exclusive scan of 4 segment sums per expert
    int run = 0;
    for (int s2 = 0; s2 < 4; ++s2) {
      const int v = SEG[s2 * NE + tid];
      SEG[s2 * NE + tid] = run;
      run += v;
    }
    CE[tid] = (float)run;  // ce[e]
  }
  __syncthreads();
  {  // per (e,seg): exclusive scan within segment
    int run = SEG[seg * NE + e];
    for (int c = seg * 32; c < seg * 32 + 32; ++c) {
      const int v = H[c * NE + e];
      H[c * NE + e] = run;
      run += v;
    }
  }
  if (tid < 64) {  // l_aux
    float p = (MEp[tid] + MEp[NE + tid] + MEp[2 * NE + tid] + MEp[3 * NE + tid])
              * CE[tid];
#pragma unroll
    for (int off = 32; off > 0; off >>= 1) p += __shfl_down(p, off);
    if (tid == 0) out[0] = p * ((float)NE / ((float)TOK * (float)TOK));
  }
  __syncthreads();
#pragma unroll 4
  for (int i = tid; i < TOK; i += 256) {  // locations1_s
    const int ex = idx_int[i];
    out[1 + TOK + i] = (float)(H[(i >> 6) * NE + ex] + rankp[i]);
  }
}

extern "C" void kernel_launch(void* const* d_in, const int* in_sizes, int n_in,
                              void* d_out, int out_size, void* d_ws, size_t ws_size,
                              hipStream_t stream) {
  const float* A = (const float*)d_in[0];   // [8192, 4096] fp32
  const float* W = (const float*)d_in[1];   // [64, 4096] fp32
  float* out = (float*)d_out;               // 1 + 8192*3 floats
  char* ws = (char*)d_ws;

  float* partial = (float*)ws;                                  // 16 MB
  const size_t poff = (size_t)KS * TOK * NE * sizeof(float);
  float* me_part = (float*)(ws + poff);                         // NCH*NE floats
  int*  idx_int = (int*)(ws + poff + NCH * NE * sizeof(float));
  int*  rankp   = idx_int + TOK;
  int*  hist    = rankp + TOK;

  hipLaunchKernelGGL(gemm_split, dim3(NT * KS), dim3(256), 0, stream, A, W, partial);
  hipLaunchKernelGGL(gating, dim3(NCH), dim3(256), 0, stream, partial, out,
                     idx_int, rankp, hist, me_part);
  hipLaunchKernelGGL(finalize, dim3(1), dim3(256), 0, stream, idx_int, rankp,
                     hist, me_part, out);
}